// Round 12
// baseline (2080.783 us; speedup 1.0000x reference)
//
#include <hip/hip_runtime.h>
#include <math.h>

#define Ee   200
#define Hh   128
#define G4   512          // 4*H
#define Kk   24
#define Bb   64
#define Tt   1024
#define HIDd 256
#define NEGf (-10000.0f)
#define PSTR 9            // partial-sum LDS stride (odd -> conflict-free)

// ---------------------------------------------------------------------------
// K0: Wt[k][n] (k<200, n<1024): n<512 -> W_ih_f[n][k], else W_ih_b[n-512][k]
// ---------------------------------------------------------------------------
__global__ __launch_bounds__(256) void k_wt(const float* __restrict__ Wf,
                                            const float* __restrict__ Wb,
                                            float* __restrict__ Wt) {
    int idx = blockIdx.x * 256 + threadIdx.x;
    if (idx >= Ee * 1024) return;
    int k = idx >> 10, n = idx & 1023;
    Wt[idx] = (n < G4) ? Wf[n * Ee + k] : Wb[(n - G4) * Ee + k];
}

// ---------------------------------------------------------------------------
// K1: fused gather+GEMM, BM=128 BN=256 BK=8, register-prefetch double buffer
//   (proven rounds 4/9/11 — unchanged).
// ---------------------------------------------------------------------------
__global__ __launch_bounds__(256, 2) void k_gemm2(const int* __restrict__ sent,
                                                  const float* __restrict__ emb,
                                                  const float* __restrict__ Wt,
                                                  float* __restrict__ Uc,
                                                  int c0T, int CT, int unified) {
    __shared__ float As[8][128];
    __shared__ float Bs[8][256];
    __shared__ int   toks[128];

    int tid = threadIdx.x;
    int n0  = blockIdx.x * 256;
    int m0  = blockIdx.y * 128;
    int dz  = blockIdx.z;
    int ty  = tid >> 4, tx = tid & 15;

    if (tid < 128) {
        int m = m0 + tid;
        int it = m >> 6, b = m & 63;
        int t = unified ? it : (dz ? (Tt - 1 - (c0T + it)) : (c0T + it));
        toks[tid] = sent[b * Tt + t];
    }
    __syncthreads();

    int am = tid & 127, ak4 = tid >> 7;
    int brow = tid >> 5, bc4 = tid & 31;

    const float* aptr = emb + (size_t)toks[am] * Ee + ak4 * 4;
    int bcol0 = (unified ? 0 : dz * G4) + n0;
    const float* bptr = Wt + (size_t)brow * 1024 + bcol0 + bc4 * 4;

    float acc[8][16];
#pragma unroll
    for (int i = 0; i < 8; ++i)
#pragma unroll
        for (int j = 0; j < 16; ++j) acc[i][j] = 0.f;

    float4 av  = *(const float4*)(aptr);
    float4 bv0 = *(const float4*)(bptr);
    float4 bv1 = *(const float4*)(bptr + 128);

    for (int kc = 0; kc < Ee; kc += 8) {
        As[ak4 * 4 + 0][am] = av.x;
        As[ak4 * 4 + 1][am] = av.y;
        As[ak4 * 4 + 2][am] = av.z;
        As[ak4 * 4 + 3][am] = av.w;
        *(float4*)&Bs[brow][bc4 * 4]       = bv0;
        *(float4*)&Bs[brow][128 + bc4 * 4] = bv1;
        __syncthreads();

        if (kc + 8 < Ee) {
            av  = *(const float4*)(aptr + kc + 8);
            bv0 = *(const float4*)(bptr + (size_t)(kc + 8) * 1024);
            bv1 = *(const float4*)(bptr + (size_t)(kc + 8) * 1024 + 128);
        }

#pragma unroll
        for (int k = 0; k < 8; ++k) {
            float a_[8], b_[16];
            *(float4*)&a_[0] = *(const float4*)&As[k][ty * 8];
            *(float4*)&a_[4] = *(const float4*)&As[k][ty * 8 + 4];
#pragma unroll
            for (int q = 0; q < 4; ++q)
                *(float4*)&b_[4 * q] = *(const float4*)&Bs[k][tx * 4 + 64 * q];
#pragma unroll
            for (int i = 0; i < 8; ++i)
#pragma unroll
                for (int j = 0; j < 16; ++j)
                    acc[i][j] = fmaf(a_[i], b_[j], acc[i][j]);
        }
        __syncthreads();
    }

    int dd   = unified ? (n0 >> 9) : dz;
    int ncol = unified ? (n0 & 511) : n0;
    float* base = Uc + (size_t)dd * ((size_t)CT * Bb * G4);
#pragma unroll
    for (int i = 0; i < 8; ++i) {
        float* dst = base + (size_t)(m0 + ty * 8 + i) * G4 + ncol + tx * 4;
#pragma unroll
        for (int q = 0; q < 4; ++q)
            *(float4*)(dst + 64 * q) = make_float4(acc[i][4 * q], acc[i][4 * q + 1],
                                                   acc[i][4 * q + 2], acc[i][4 * q + 3]);
    }
}

// ---------------------------------------------------------------------------
// K2: paired-chain LSTM. 64 blocks = (d, batch-pair), 512 thr (8 waves).
//   Two SAME-direction chains (bA=2p, bB=2p+1) share the W_hh registers
//   (w[8][16] loaded once) -> per-thread VGPR ~200, no spill, while VALU
//   issue per step doubles inside the same barrier skeleton. Per-chain math
//   is byte-identical to the proven v2 k_lstm2 (same ps layout, same reduce
//   order, same activations) => bit-identical output, conflicts stay 0.
//   P3 roles: cellA waves 0-1, tagA wave 2, cellB waves 4-5, tagB wave 6.
// ---------------------------------------------------------------------------
__global__ __launch_bounds__(512, 2) void k_lstm2b(const float* __restrict__ Uc,
                                                   const float* __restrict__ Whh_f,
                                                   const float* __restrict__ Whh_b,
                                                   const float* __restrict__ bih_f,
                                                   const float* __restrict__ bhh_f,
                                                   const float* __restrict__ bih_b,
                                                   const float* __restrict__ bhh_b,
                                                   const float* __restrict__ h0v,
                                                   const float* __restrict__ c0v,
                                                   const float* __restrict__ Wout,
                                                   float* __restrict__ hst,
                                                   float* __restrict__ cst,
                                                   float* __restrict__ pf,
                                                   int c0T, int CT, int first,
                                                   int unified) {
    __shared__ float hshA[Hh], hshB[Hh];
    __shared__ float gshA[G4], gshB[G4];
    __shared__ float psA[(G4 + Kk) * PSTR];
    __shared__ float psB[(G4 + Kk) * PSTR];

    int tid  = threadIdx.x;
    int lane = tid & 63, wv = tid >> 6;
    int d  = blockIdx.x >> 5;
    int pr = blockIdx.x & 31;
    int bA = pr * 2, bB = pr * 2 + 1;

    const float* Whh = d ? Whh_b : Whh_f;
    float bias = d ? (bih_b[tid] + bhh_b[tid]) : (bih_f[tid] + bhh_f[tid]);

    // shared-weight registers (identical for both chains)
    float w[8][16];
#pragma unroll
    for (int ri = 0; ri < 8; ++ri) {
        const float* wr = Whh + (size_t)(ri * 64 + lane) * Hh + wv * 16;
#pragma unroll
        for (int c4 = 0; c4 < 4; ++c4)
            *(float4*)&w[ri][c4 * 4] = *(const float4*)(wr + c4 * 4);
    }
    float wt[16];
    if (lane < Kk) {
        const float* wr = Wout + (size_t)lane * HIDd + d * Hh + wv * 16;
#pragma unroll
        for (int c4 = 0; c4 < 4; ++c4)
            *(float4*)&wt[c4 * 4] = *(const float4*)(wr + c4 * 4);
    }

    float ccA = 0.f, ccB = 0.f;
    if (tid < Hh) {
        int si = (d * Bb + bA) * Hh + tid;
        hshA[tid] = first ? h0v[si] : hst[si];
        ccA       = first ? c0v[si] : cst[si];
    }
    if (tid >= 256 && tid < 256 + Hh) {
        int j = tid - 256;
        int si = (d * Bb + bB) * Hh + j;
        hshB[j] = first ? h0v[si] : hst[si];
        ccB     = first ? c0v[si] : cst[si];
    }
    __syncthreads();

    const float* Ub = Uc + (size_t)d * ((size_t)CT * Bb * G4);
    int u0 = unified ? (d ? (Tt - 1) : 0) : 0;
    int us = unified ? (d ? -1 : 1) : 1;

    float ucurA = Ub[(size_t)u0 * (Bb * G4) + bA * G4 + tid];
    float ucurB = Ub[(size_t)u0 * (Bb * G4) + bB * G4 + tid];
    float unextA = 0.f, unextB = 0.f;

    for (int i = 0; i <= CT; ++i) {
        int last = (i == CT);
        // ---- P1: partial dots for both chains off h(i-1) ----
        float hvA[16], hvB[16];
        *(float4*)&hvA[0]  = *(const float4*)&hshA[wv * 16];
        *(float4*)&hvA[4]  = *(const float4*)&hshA[wv * 16 + 4];
        *(float4*)&hvA[8]  = *(const float4*)&hshA[wv * 16 + 8];
        *(float4*)&hvA[12] = *(const float4*)&hshA[wv * 16 + 12];
        *(float4*)&hvB[0]  = *(const float4*)&hshB[wv * 16];
        *(float4*)&hvB[4]  = *(const float4*)&hshB[wv * 16 + 4];
        *(float4*)&hvB[8]  = *(const float4*)&hshB[wv * 16 + 8];
        *(float4*)&hvB[12] = *(const float4*)&hshB[wv * 16 + 12];

        if (lane < Kk) {
            float sA = 0.f, sB = 0.f;
#pragma unroll
            for (int c = 0; c < 16; ++c) {
                sA = fmaf(wt[c], hvA[c], sA);
                sB = fmaf(wt[c], hvB[c], sB);
            }
            psA[(G4 + lane) * PSTR + wv] = sA;
            psB[(G4 + lane) * PSTR + wv] = sB;
        }
        if (!last) {
#pragma unroll
            for (int ri = 0; ri < 8; ++ri) {
                float sA = 0.f, sB = 0.f;
#pragma unroll
                for (int c = 0; c < 16; ++c) {
                    sA = fmaf(w[ri][c], hvA[c], sA);
                    sB = fmaf(w[ri][c], hvB[c], sB);
                }
                psA[(ri * 64 + lane) * PSTR + wv] = sA;
                psB[(ri * 64 + lane) * PSTR + wv] = sB;
            }
            if (i + 1 < CT) {
                const float* un = Ub + (size_t)(u0 + (i + 1) * us) * (Bb * G4);
                unextA = un[bA * G4 + tid];
                unextB = un[bB * G4 + tid];
            }
        }
        __syncthreads();

        // ---- P2: reduce + activate for both chains (thread tid owns gate tid)
        if (!last) {
            const float* prA = psA + (size_t)tid * PSTR;
            const float* prB = psB + (size_t)tid * PSTR;
            float sA = ((prA[0] + prA[1]) + (prA[2] + prA[3])) +
                       ((prA[4] + prA[5]) + (prA[6] + prA[7]));
            float sB = ((prB[0] + prB[1]) + (prB[2] + prB[3])) +
                       ((prB[4] + prB[5]) + (prB[6] + prB[7]));
            sA += ucurA + bias;
            sB += ucurB + bias;
            int gt = tid >> 7;                      // 0:i 1:f 2:g 3:o
            if (gt == 2) {
                gshA[tid] = tanhf(sA);
                gshB[tid] = tanhf(sB);
            } else {
                gshA[tid] = 1.f / (1.f + expf(-sA));
                gshB[tid] = 1.f / (1.f + expf(-sB));
            }
        }
        __syncthreads();

        // ---- P3: cells (waves 0-1 / 4-5) + tag emits (waves 2 / 6) ----
        if (!last && tid < Hh) {
            float gi = gshA[tid], gf = gshA[Hh + tid];
            float gg = gshA[2 * Hh + tid], go = gshA[3 * Hh + tid];
            ccA = gf * ccA + gi * gg;
            hshA[tid] = go * tanhf(ccA);
        }
        if (!last && tid >= 256 && tid < 256 + Hh) {
            int j = tid - 256;
            float gi = gshB[j], gf = gshB[Hh + j];
            float gg = gshB[2 * Hh + j], go = gshB[3 * Hh + j];
            ccB = gf * ccB + gi * gg;
            hshB[j] = go * tanhf(ccB);
        }
        if (tid >= 128 && tid < 128 + Kk && i >= 1) {
            int k = tid - 128;
            const float* prt = psA + (size_t)(G4 + k) * PSTR;
            float s = ((prt[0] + prt[1]) + (prt[2] + prt[3])) +
                      ((prt[4] + prt[5]) + (prt[6] + prt[7]));
            int tp = c0T + i - 1;
            int tg = d ? (Tt - 1 - tp) : tp;
            pf[((size_t)(d * Bb + bA) * Tt + tg) * Kk + k] = s;
        }
        if (tid >= 384 && tid < 384 + Kk && i >= 1) {
            int k = tid - 384;
            const float* prt = psB + (size_t)(G4 + k) * PSTR;
            float s = ((prt[0] + prt[1]) + (prt[2] + prt[3])) +
                      ((prt[4] + prt[5]) + (prt[6] + prt[7]));
            int tp = c0T + i - 1;
            int tg = d ? (Tt - 1 - tp) : tp;
            pf[((size_t)(d * Bb + bB) * Tt + tg) * Kk + k] = s;
        }
        __syncthreads();
        ucurA = unextA;
        ucurB = unextB;
    }

    if (tid < Hh) {
        int si = (d * Bb + bA) * Hh + tid;
        hst[si] = hshA[tid];
        cst[si] = ccA;
    }
    if (tid >= 256 && tid < 256 + Hh) {
        int j = tid - 256;
        int si = (d * Bb + bB) * Hh + j;
        hst[si] = hshB[j];
        cst[si] = ccB;
    }
}

// ---------------------------------------------------------------------------
// K3: Viterbi, tree-argmax + 64-step LDS-staged feats (proven round 9/11)
// ---------------------------------------------------------------------------
#define CMB(av, ai, bv_, bi_, ov, oi)                         \
    { bool g = (bv_) > (av); ov = g ? (bv_) : (av); oi = g ? (bi_) : (ai); }

__global__ __launch_bounds__(64) void k_viterbi(const float* __restrict__ pf,
                                                const float* __restrict__ bout,
                                                const float* __restrict__ trans,
                                                float* __restrict__ out) {
    __shared__ unsigned char bptr[Tt * Kk];
    __shared__ float fsh[2][64][25];
    __shared__ float tsh[Kk];
    __shared__ unsigned char path[Tt];

    int lane = threadIdx.x;
    int b    = blockIdx.x;
    int half   = (lane >= Kk) ? 1 : 0;
    int n      = half ? (lane - Kk) : lane;
    int active = (lane < 2 * Kk);

    float tr[12];
    float bo = 0.f;
    if (active) {
#pragma unroll
        for (int j = 0; j < 12; ++j) tr[j] = trans[n * Kk + half * 12 + j];
        bo = bout[n];
    }
    float v = (lane == 0) ? 0.f : NEGf;   // START=0

    const float* p0 = pf + (size_t)b * Tt * Kk;
    const float* p1 = pf + (size_t)(Bb + b) * Tt * Kk;

    float4 r0[6], r1[6];
#pragma unroll
    for (int j = 0; j < 6; ++j) {
        int f = 4 * (lane + 64 * j);
        r0[j] = *(const float4*)(p0 + f);
        r1[j] = *(const float4*)(p1 + f);
    }
#pragma unroll
    for (int j = 0; j < 6; ++j) {
        int f = 4 * (lane + 64 * j);
        int s = f / 24, k = f - 24 * s;
        fsh[0][s][k + 0] = r0[j].x + r1[j].x;
        fsh[0][s][k + 1] = r0[j].y + r1[j].y;
        fsh[0][s][k + 2] = r0[j].z + r1[j].z;
        fsh[0][s][k + 3] = r0[j].w + r1[j].w;
    }

    for (int c = 0; c < 16; ++c) {
        int cur = c & 1;
        if (c + 1 < 16) {
            const float* q0 = p0 + (c + 1) * 1536;
            const float* q1 = p1 + (c + 1) * 1536;
#pragma unroll
            for (int j = 0; j < 6; ++j) {
                int f = 4 * (lane + 64 * j);
                r0[j] = *(const float4*)(q0 + f);
                r1[j] = *(const float4*)(q1 + f);
            }
        }

        for (int s = 0; s < 64; ++s) {
            int t = c * 64 + s;
            if (active) {
                int pb = half * 12;
                float sc[12];
#pragma unroll
                for (int j = 0; j < 12; ++j) sc[j] = __shfl(v, pb + j) + tr[j];

                float l1v[6]; int l1i[6];
#pragma unroll
                for (int j = 0; j < 6; ++j)
                    CMB(sc[2 * j], 2 * j, sc[2 * j + 1], 2 * j + 1, l1v[j], l1i[j]);
                float l2v[3]; int l2i[3];
#pragma unroll
                for (int j = 0; j < 3; ++j)
                    CMB(l1v[2 * j], l1i[2 * j], l1v[2 * j + 1], l1i[2 * j + 1],
                        l2v[j], l2i[j]);
                float dv; int di;
                CMB(l2v[0], l2i[0], l2v[1], l2i[1], dv, di);
                float best; int bp;
                CMB(dv, di, l2v[2], l2i[2], best, bp);
                bp += pb;

                float ob  = __shfl(best, n + Kk);
                int   obp = __shfl(bp,   n + Kk);
                if (half == 0) {
                    if (ob > best) { best = ob; bp = obp; }
                    v = best + fsh[cur][s][n] + bo;
                    bptr[t * Kk + n] = (unsigned char)bp;
                }
            }
        }

        if (c + 1 < 16) {
#pragma unroll
            for (int j = 0; j < 6; ++j) {
                int f = 4 * (lane + 64 * j);
                int s = f / 24, k = f - 24 * s;
                fsh[cur ^ 1][s][k + 0] = r0[j].x + r1[j].x;
                fsh[cur ^ 1][s][k + 1] = r0[j].y + r1[j].y;
                fsh[cur ^ 1][s][k + 2] = r0[j].z + r1[j].z;
                fsh[cur ^ 1][s][k + 3] = r0[j].w + r1[j].w;
            }
        }
    }

    if (half == 0 && lane < Kk) tsh[n] = v + trans[1 * Kk + n];   // STOP=1
    __syncthreads();

    if (lane == 0) {
        float bestv = tsh[0];
        int tag = 0;
        for (int q = 1; q < Kk; ++q)
            if (tsh[q] > bestv) { bestv = tsh[q]; tag = q; }
        out[b] = bestv;
        for (int t = Tt - 1; t >= 1; --t) {
            path[t] = (unsigned char)tag;
            tag = bptr[t * Kk + tag];
        }
        path[0] = (unsigned char)tag;
    }
    __syncthreads();

    float* otag = out + Bb + (size_t)b * Tt;
    for (int t = lane; t < Tt; t += 64) otag[t] = (float)path[t];
}

// ---------------------------------------------------------------------------
// host launcher
// ---------------------------------------------------------------------------
extern "C" void kernel_launch(void* const* d_in, const int* in_sizes, int n_in,
                              void* d_out, int out_size, void* d_ws, size_t ws_size,
                              hipStream_t stream) {
    const int*   sent  = (const int*)d_in[0];
    const float* emb   = (const float*)d_in[2];
    const float* Wih_f = (const float*)d_in[3];
    const float* Whh_f = (const float*)d_in[4];
    const float* bih_f = (const float*)d_in[5];
    const float* bhh_f = (const float*)d_in[6];
    const float* Wih_b = (const float*)d_in[7];
    const float* Whh_b = (const float*)d_in[8];
    const float* bih_b = (const float*)d_in[9];
    const float* bhh_b = (const float*)d_in[10];
    const float* h0    = (const float*)d_in[11];
    const float* c0    = (const float*)d_in[12];
    const float* Wout  = (const float*)d_in[13];
    const float* bout  = (const float*)d_in[14];
    const float* trans = (const float*)d_in[15];

    float* ws  = (float*)d_ws;
    float* Wt  = ws;                       //   204,800 f
    float* pf  = Wt + 204800;              // 3,145,728 f
    float* hst = pf + 3145728;             //    16,384 f
    float* cst = hst + 16384;              //    16,384 f
    float* Uc  = cst + 16384;

    const size_t fixedf = 204800 + 3145728 + 16384 + 16384;
    size_t needU = (size_t)2 * Tt * Bb * G4;
    int unified = ((fixedf + needU) * 4 <= ws_size);

    k_wt<<<(Ee * 1024 + 255) / 256, 256, 0, stream>>>(Wih_f, Wih_b, Wt);

    if (unified) {
        k_gemm2<<<dim3(4, 512, 1), 256, 0, stream>>>(sent, emb, Wt, Uc, 0, Tt, 1);
        k_lstm2b<<<64, 512, 0, stream>>>(Uc, Whh_f, Whh_b, bih_f, bhh_f,
                                         bih_b, bhh_b, h0, c0, Wout,
                                         hst, cst, pf, 0, Tt, 1, 1);
    } else {
        int CT = 64;
        const int cands[3] = {512, 256, 128};
        for (int ci = 0; ci < 3; ++ci)
            if ((fixedf + (size_t)2 * cands[ci] * Bb * G4) * 4 <= ws_size) {
                CT = cands[ci]; break;
            }
        int NC = Tt / CT;
        for (int cix = 0; cix < NC; ++cix) {
            k_gemm2<<<dim3(2, CT * 64 / 128, 2), 256, 0, stream>>>(
                sent, emb, Wt, Uc, cix * CT, CT, 0);
            k_lstm2b<<<64, 512, 0, stream>>>(Uc, Whh_f, Whh_b, bih_f, bhh_f,
                                             bih_b, bhh_b, h0, c0, Wout,
                                             hst, cst, pf, cix * CT, CT,
                                             cix == 0, 0);
        }
    }

    k_viterbi<<<Bb, 64, 0, stream>>>(pf, bout, trans, (float*)d_out);
}

// Round 13
// 1826.043 us; speedup vs baseline: 1.1395x; 1.1395x over previous
//
#include <hip/hip_runtime.h>
#include <math.h>

#define Ee   200
#define Hh   128
#define G4   512          // 4*H
#define Kk   24
#define Bb   64
#define Tt   1024
#define HIDd 256
#define NEGf (-10000.0f)
#define PSV  520          // ps per-producer-wave stride (mod 32 = 8)

// ---------------------------------------------------------------------------
// K0: Wt[k][n] (k<200, n<1024): n<512 -> W_ih_f[n][k], else W_ih_b[n-512][k]
// ---------------------------------------------------------------------------
__global__ __launch_bounds__(256) void k_wt(const float* __restrict__ Wf,
                                            const float* __restrict__ Wb,
                                            float* __restrict__ Wt) {
    int idx = blockIdx.x * 256 + threadIdx.x;
    if (idx >= Ee * 1024) return;
    int k = idx >> 10, n = idx & 1023;
    Wt[idx] = (n < G4) ? Wf[n * Ee + k] : Wb[(n - G4) * Ee + k];
}

// ---------------------------------------------------------------------------
// K1: fused gather+GEMM, BM=128 BN=256 BK=8, register-prefetch double buffer
//   (proven rounds 4/9/11 — unchanged).
// ---------------------------------------------------------------------------
__global__ __launch_bounds__(256, 2) void k_gemm2(const int* __restrict__ sent,
                                                  const float* __restrict__ emb,
                                                  const float* __restrict__ Wt,
                                                  float* __restrict__ Uc,
                                                  int c0T, int CT, int unified) {
    __shared__ float As[8][128];
    __shared__ float Bs[8][256];
    __shared__ int   toks[128];

    int tid = threadIdx.x;
    int n0  = blockIdx.x * 256;
    int m0  = blockIdx.y * 128;
    int dz  = blockIdx.z;
    int ty  = tid >> 4, tx = tid & 15;

    if (tid < 128) {
        int m = m0 + tid;
        int it = m >> 6, b = m & 63;
        int t = unified ? it : (dz ? (Tt - 1 - (c0T + it)) : (c0T + it));
        toks[tid] = sent[b * Tt + t];
    }
    __syncthreads();

    int am = tid & 127, ak4 = tid >> 7;
    int brow = tid >> 5, bc4 = tid & 31;

    const float* aptr = emb + (size_t)toks[am] * Ee + ak4 * 4;
    int bcol0 = (unified ? 0 : dz * G4) + n0;
    const float* bptr = Wt + (size_t)brow * 1024 + bcol0 + bc4 * 4;

    float acc[8][16];
#pragma unroll
    for (int i = 0; i < 8; ++i)
#pragma unroll
        for (int j = 0; j < 16; ++j) acc[i][j] = 0.f;

    float4 av  = *(const float4*)(aptr);
    float4 bv0 = *(const float4*)(bptr);
    float4 bv1 = *(const float4*)(bptr + 128);

    for (int kc = 0; kc < Ee; kc += 8) {
        As[ak4 * 4 + 0][am] = av.x;
        As[ak4 * 4 + 1][am] = av.y;
        As[ak4 * 4 + 2][am] = av.z;
        As[ak4 * 4 + 3][am] = av.w;
        *(float4*)&Bs[brow][bc4 * 4]       = bv0;
        *(float4*)&Bs[brow][128 + bc4 * 4] = bv1;
        __syncthreads();

        if (kc + 8 < Ee) {
            av  = *(const float4*)(aptr + kc + 8);
            bv0 = *(const float4*)(bptr + (size_t)(kc + 8) * 1024);
            bv1 = *(const float4*)(bptr + (size_t)(kc + 8) * 1024 + 128);
        }

#pragma unroll
        for (int k = 0; k < 8; ++k) {
            float a_[8], b_[16];
            *(float4*)&a_[0] = *(const float4*)&As[k][ty * 8];
            *(float4*)&a_[4] = *(const float4*)&As[k][ty * 8 + 4];
#pragma unroll
            for (int q = 0; q < 4; ++q)
                *(float4*)&b_[4 * q] = *(const float4*)&Bs[k][tx * 4 + 64 * q];
#pragma unroll
            for (int i = 0; i < 8; ++i)
#pragma unroll
                for (int j = 0; j < 16; ++j)
                    acc[i][j] = fmaf(a_[i], b_[j], acc[i][j]);
        }
        __syncthreads();
    }

    int dd   = unified ? (n0 >> 9) : dz;
    int ncol = unified ? (n0 & 511) : n0;
    float* base = Uc + (size_t)dd * ((size_t)CT * Bb * G4);
#pragma unroll
    for (int i = 0; i < 8; ++i) {
        float* dst = base + (size_t)(m0 + ty * 8 + i) * G4 + ncol + tx * 4;
#pragma unroll
        for (int q = 0; q < 4; ++q)
            *(float4*)(dst + 64 * q) = make_float4(acc[i][4 * q], acc[i][4 * q + 1],
                                                   acc[i][4 * q + 2], acc[i][4 * q + 3]);
    }
}

// ---------------------------------------------------------------------------
// K2: k_lstm6 — v2's P1 + permuted ps so the 4 gate rows of cell j land in
//   4 adjacent lanes of one wave. Cell update is then in-wave (3 shfl), no
//   gsh round-trip, 2 barriers/step. Layout:
//     row r = g*128 + 16w + m  (g=gate, w=owner wave, m=cell-in-wave)
//     pi(r) = ((g*4 | (w>>1))<<5) | (((w^g)&1)<<4) | m ;  slot = v*520+pi(r)
//   Banks: P1 write (fixed g,v; varying l): m + 16*(w&1) -> 2-way (free).
//          P2 read  (fixed w,v; lane=4m+g): m + 16*(g&1) -> 2-way (free).
//   Reduce order, operand order, activations identical to v2 k_lstm2.
//   Tags: v2 partials into 2-phase-buffered tb, reduced next step's P1 by
//   wave-2 lanes (+ epilogue).
// ---------------------------------------------------------------------------
__global__ __launch_bounds__(512, 2) void k_lstm6(const float* __restrict__ Uc,
                                                  const float* __restrict__ Whh_f,
                                                  const float* __restrict__ Whh_b,
                                                  const float* __restrict__ bih_f,
                                                  const float* __restrict__ bhh_f,
                                                  const float* __restrict__ bih_b,
                                                  const float* __restrict__ bhh_b,
                                                  const float* __restrict__ h0v,
                                                  const float* __restrict__ c0v,
                                                  const float* __restrict__ Wout,
                                                  float* __restrict__ hst,
                                                  float* __restrict__ cst,
                                                  float* __restrict__ pf,
                                                  int c0T, int CT, int first,
                                                  int unified) {
    __shared__ float hsh[Hh];
    __shared__ float ps[8 * PSV];
    __shared__ float tb[2 * 216];

    int tid  = threadIdx.x;
    int lane = tid & 63, wv = tid >> 6;
    int b = blockIdx.x & 63, d = blockIdx.x >> 6;

    const float* Whh = d ? Whh_b : Whh_f;
    const float* bih = d ? bih_b : bih_f;
    const float* bhh = d ? bhh_b : bhh_f;

    // P1 weights (v2 layout): rows 64*ri+lane, cols [16wv,16wv+16)
    float w[8][16];
#pragma unroll
    for (int ri = 0; ri < 8; ++ri) {
        const float* wr = Whh + (size_t)(ri * 64 + lane) * Hh + wv * 16;
#pragma unroll
        for (int c4 = 0; c4 < 4; ++c4)
            *(float4*)&w[ri][c4 * 4] = *(const float4*)(wr + c4 * 4);
    }
    float wt[16];
    if (lane < Kk) {
        const float* wr = Wout + (size_t)lane * HIDd + d * Hh + wv * 16;
#pragma unroll
        for (int c4 = 0; c4 < 4; ++c4)
            *(float4*)&wt[c4 * 4] = *(const float4*)(wr + c4 * 4);
    }

    // P1 write slots (precomputed, step-invariant)
    int addrW[8];
#pragma unroll
    for (int ri = 0; ri < 8; ++ri) {
        int r = ri * 64 + lane;
        int g = r >> 7, ww = (r & 127) >> 4, m = r & 15;
        addrW[ri] = wv * PSV + ((((g << 2) | (ww >> 1)) << 5) |
                                (((ww ^ g) & 1) << 4) | m);
    }

    // P2 ownership: lane = 4m+g of wave wv owns row g*128 + 16wv + m
    int gOwn = lane & 3, mOwn = lane >> 2;
    int rOwn = gOwn * 128 + 16 * wv + mOwn;
    int piR  = ((((gOwn << 2) | (wv >> 1)) << 5) |
                (((wv ^ gOwn) & 1) << 4) | mOwn);
    float biasOwn = bih[rOwn] + bhh[rOwn];

    float cc = 0.f;
    if (tid < Hh) {
        int si = (d * Bb + b) * Hh + tid;
        hsh[tid] = first ? h0v[si] : hst[si];
    }
    if (gOwn == 0) {
        int ci = 16 * wv + mOwn;
        int si = (d * Bb + b) * Hh + ci;
        cc = first ? c0v[si] : cst[si];
    }
    __syncthreads();

    const float* Ub = Uc + (size_t)d * ((size_t)CT * Bb * G4);
    int u0 = unified ? (d ? (Tt - 1) : 0) : 0;
    int us = unified ? (d ? -1 : 1) : 1;

    float ucur  = Ub[(size_t)u0 * (Bb * G4) + b * G4 + rOwn];
    float unext = 0.f;

    for (int i = 0; i <= CT; ++i) {
        int last = (i == CT);
        // ---- P1: partial dots off hsh = h(i-1) ----
        float hv[16];
        *(float4*)&hv[0]  = *(const float4*)&hsh[wv * 16];
        *(float4*)&hv[4]  = *(const float4*)&hsh[wv * 16 + 4];
        *(float4*)&hv[8]  = *(const float4*)&hsh[wv * 16 + 8];
        *(float4*)&hv[12] = *(const float4*)&hsh[wv * 16 + 12];

        if (lane < Kk) {                       // tag partials of h(i-1)
            float s = 0.f;
#pragma unroll
            for (int c = 0; c < 16; ++c) s = fmaf(wt[c], hv[c], s);
            tb[(i & 1) * 216 + lane * 9 + wv] = s;
        }
        if (!last) {
#pragma unroll
            for (int ri = 0; ri < 8; ++ri) {
                float s = 0.f;
#pragma unroll
                for (int c = 0; c < 16; ++c) s = fmaf(w[ri][c], hv[c], s);
                ps[addrW[ri]] = s;
            }
            if (i + 1 < CT)
                unext = Ub[(size_t)(u0 + (i + 1) * us) * (Bb * G4) + b * G4 + rOwn];
        }
        // tag reduce of h(i-2) partials (written step i-1, barrier since)
        if (i >= 2 && tid >= 128 && tid < 128 + Kk) {
            int k = tid - 128;
            const float* q = tb + ((i - 1) & 1) * 216 + k * 9;
            float s = ((q[0] + q[1]) + (q[2] + q[3])) +
                      ((q[4] + q[5]) + (q[6] + q[7]));
            int tp = c0T + i - 2;
            int tg = d ? (Tt - 1 - tp) : tp;
            pf[((size_t)(d * Bb + b) * Tt + tg) * Kk + k] = s;
        }
        __syncthreads();

        // ---- P2: reduce own row + activate + in-wave cell ----
        if (!last) {
            const float* pr = ps + piR;
            float s = ((pr[0 * PSV] + pr[1 * PSV]) + (pr[2 * PSV] + pr[3 * PSV])) +
                      ((pr[4 * PSV] + pr[5 * PSV]) + (pr[6 * PSV] + pr[7 * PSV]));
            s += ucur + biasOwn;
            float a = (gOwn == 2) ? tanhf(s) : 1.f / (1.f + expf(-s));

            int base = lane & ~3;
            float fx = __shfl(a, base + 1);
            float gx = __shfl(a, base + 2);
            float ox = __shfl(a, base + 3);
            if (gOwn == 0) {
                cc = fx * cc + a * gx;            // gf*cc + gi*gg (v2 order)
                hsh[16 * wv + mOwn] = ox * tanhf(cc);
            }
            ucur = unext;
        }
        __syncthreads();
    }

    // epilogue: reduce tag partials of h(CT-1) (written at i=CT)
    if (tid >= 128 && tid < 128 + Kk) {
        int k = tid - 128;
        const float* q = tb + (CT & 1) * 216 + k * 9;
        float s = ((q[0] + q[1]) + (q[2] + q[3])) +
                  ((q[4] + q[5]) + (q[6] + q[7]));
        int tp = c0T + CT - 1;
        int tg = d ? (Tt - 1 - tp) : tp;
        pf[((size_t)(d * Bb + b) * Tt + tg) * Kk + k] = s;
    }
    if (tid < Hh) {
        int si = (d * Bb + b) * Hh + tid;
        hst[si] = hsh[tid];
    }
    if (gOwn == 0) {
        int ci = 16 * wv + mOwn;
        cst[(d * Bb + b) * Hh + ci] = cc;
    }
}

// ---------------------------------------------------------------------------
// K3: Viterbi, tree-argmax + 64-step LDS-staged feats (proven round 9/11)
// ---------------------------------------------------------------------------
#define CMB(av, ai, bv_, bi_, ov, oi)                         \
    { bool g = (bv_) > (av); ov = g ? (bv_) : (av); oi = g ? (bi_) : (ai); }

__global__ __launch_bounds__(64) void k_viterbi(const float* __restrict__ pf,
                                                const float* __restrict__ bout,
                                                const float* __restrict__ trans,
                                                float* __restrict__ out) {
    __shared__ unsigned char bptr[Tt * Kk];
    __shared__ float fsh[2][64][25];
    __shared__ float tsh[Kk];
    __shared__ unsigned char path[Tt];

    int lane = threadIdx.x;
    int b    = blockIdx.x;
    int half   = (lane >= Kk) ? 1 : 0;
    int n      = half ? (lane - Kk) : lane;
    int active = (lane < 2 * Kk);

    float tr[12];
    float bo = 0.f;
    if (active) {
#pragma unroll
        for (int j = 0; j < 12; ++j) tr[j] = trans[n * Kk + half * 12 + j];
        bo = bout[n];
    }
    float v = (lane == 0) ? 0.f : NEGf;   // START=0

    const float* p0 = pf + (size_t)b * Tt * Kk;
    const float* p1 = pf + (size_t)(Bb + b) * Tt * Kk;

    float4 r0[6], r1[6];
#pragma unroll
    for (int j = 0; j < 6; ++j) {
        int f = 4 * (lane + 64 * j);
        r0[j] = *(const float4*)(p0 + f);
        r1[j] = *(const float4*)(p1 + f);
    }
#pragma unroll
    for (int j = 0; j < 6; ++j) {
        int f = 4 * (lane + 64 * j);
        int s = f / 24, k = f - 24 * s;
        fsh[0][s][k + 0] = r0[j].x + r1[j].x;
        fsh[0][s][k + 1] = r0[j].y + r1[j].y;
        fsh[0][s][k + 2] = r0[j].z + r1[j].z;
        fsh[0][s][k + 3] = r0[j].w + r1[j].w;
    }

    for (int c = 0; c < 16; ++c) {
        int cur = c & 1;
        if (c + 1 < 16) {
            const float* q0 = p0 + (c + 1) * 1536;
            const float* q1 = p1 + (c + 1) * 1536;
#pragma unroll
            for (int j = 0; j < 6; ++j) {
                int f = 4 * (lane + 64 * j);
                r0[j] = *(const float4*)(q0 + f);
                r1[j] = *(const float4*)(q1 + f);
            }
        }

        for (int s = 0; s < 64; ++s) {
            int t = c * 64 + s;
            if (active) {
                int pb = half * 12;
                float sc[12];
#pragma unroll
                for (int j = 0; j < 12; ++j) sc[j] = __shfl(v, pb + j) + tr[j];

                float l1v[6]; int l1i[6];
#pragma unroll
                for (int j = 0; j < 6; ++j)
                    CMB(sc[2 * j], 2 * j, sc[2 * j + 1], 2 * j + 1, l1v[j], l1i[j]);
                float l2v[3]; int l2i[3];
#pragma unroll
                for (int j = 0; j < 3; ++j)
                    CMB(l1v[2 * j], l1i[2 * j], l1v[2 * j + 1], l1i[2 * j + 1],
                        l2v[j], l2i[j]);
                float dv; int di;
                CMB(l2v[0], l2i[0], l2v[1], l2i[1], dv, di);
                float best; int bp;
                CMB(dv, di, l2v[2], l2i[2], best, bp);
                bp += pb;

                float ob  = __shfl(best, n + Kk);
                int   obp = __shfl(bp,   n + Kk);
                if (half == 0) {
                    if (ob > best) { best = ob; bp = obp; }
                    v = best + fsh[cur][s][n] + bo;
                    bptr[t * Kk + n] = (unsigned char)bp;
                }
            }
        }

        if (c + 1 < 16) {
#pragma unroll
            for (int j = 0; j < 6; ++j) {
                int f = 4 * (lane + 64 * j);
                int s = f / 24, k = f - 24 * s;
                fsh[cur ^ 1][s][k + 0] = r0[j].x + r1[j].x;
                fsh[cur ^ 1][s][k + 1] = r0[j].y + r1[j].y;
                fsh[cur ^ 1][s][k + 2] = r0[j].z + r1[j].z;
                fsh[cur ^ 1][s][k + 3] = r0[j].w + r1[j].w;
            }
        }
    }

    if (half == 0 && lane < Kk) tsh[n] = v + trans[1 * Kk + n];   // STOP=1
    __syncthreads();

    if (lane == 0) {
        float bestv = tsh[0];
        int tag = 0;
        for (int q = 1; q < Kk; ++q)
            if (tsh[q] > bestv) { bestv = tsh[q]; tag = q; }
        out[b] = bestv;
        for (int t = Tt - 1; t >= 1; --t) {
            path[t] = (unsigned char)tag;
            tag = bptr[t * Kk + tag];
        }
        path[0] = (unsigned char)tag;
    }
    __syncthreads();

    float* otag = out + Bb + (size_t)b * Tt;
    for (int t = lane; t < Tt; t += 64) otag[t] = (float)path[t];
}

// ---------------------------------------------------------------------------
// host launcher
// ---------------------------------------------------------------------------
extern "C" void kernel_launch(void* const* d_in, const int* in_sizes, int n_in,
                              void* d_out, int out_size, void* d_ws, size_t ws_size,
                              hipStream_t stream) {
    const int*   sent  = (const int*)d_in[0];
    const float* emb   = (const float*)d_in[2];
    const float* Wih_f = (const float*)d_in[3];
    const float* Whh_f = (const float*)d_in[4];
    const float* bih_f = (const float*)d_in[5];
    const float* bhh_f = (const float*)d_in[6];
    const float* Wih_b = (const float*)d_in[7];
    const float* Whh_b = (const float*)d_in[8];
    const float* bih_b = (const float*)d_in[9];
    const float* bhh_b = (const float*)d_in[10];
    const float* h0    = (const float*)d_in[11];
    const float* c0    = (const float*)d_in[12];
    const float* Wout  = (const float*)d_in[13];
    const float* bout  = (const float*)d_in[14];
    const float* trans = (const float*)d_in[15];

    float* ws  = (float*)d_ws;
    float* Wt  = ws;                       //   204,800 f
    float* pf  = Wt + 204800;              // 3,145,728 f
    float* hst = pf + 3145728;             //    16,384 f
    float* cst = hst + 16384;              //    16,384 f
    float* Uc  = cst + 16384;

    const size_t fixedf = 204800 + 3145728 + 16384 + 16384;
    size_t needU = (size_t)2 * Tt * Bb * G4;
    int unified = ((fixedf + needU) * 4 <= ws_size);

    k_wt<<<(Ee * 1024 + 255) / 256, 256, 0, stream>>>(Wih_f, Wih_b, Wt);

    if (unified) {
        k_gemm2<<<dim3(4, 512, 1), 256, 0, stream>>>(sent, emb, Wt, Uc, 0, Tt, 1);
        k_lstm6<<<128, 512, 0, stream>>>(Uc, Whh_f, Whh_b, bih_f, bhh_f,
                                         bih_b, bhh_b, h0, c0, Wout,
                                         hst, cst, pf, 0, Tt, 1, 1);
    } else {
        int CT = 64;
        const int cands[3] = {512, 256, 128};
        for (int ci = 0; ci < 3; ++ci)
            if ((fixedf + (size_t)2 * cands[ci] * Bb * G4) * 4 <= ws_size) {
                CT = cands[ci]; break;
            }
        int NC = Tt / CT;
        for (int cix = 0; cix < NC; ++cix) {
            k_gemm2<<<dim3(2, CT * 64 / 128, 2), 256, 0, stream>>>(
                sent, emb, Wt, Uc, cix * CT, CT, 0);
            k_lstm6<<<128, 512, 0, stream>>>(Uc, Whh_f, Whh_b, bih_f, bhh_f,
                                             bih_b, bhh_b, h0, c0, Wout,
                                             hst, cst, pf, cix * CT, CT,
                                             cix == 0, 0);
        }
    }

    k_viterbi<<<Bb, 64, 0, stream>>>(pf, bout, trans, (float*)d_out);
}

// Round 14
// 1520.293 us; speedup vs baseline: 1.3687x; 1.2011x over previous
//
#include <hip/hip_runtime.h>
#include <math.h>

#define Ee   200
#define Hh   128
#define G4   512          // 4*H
#define Kk   24
#define Bb   64
#define Tt   1024
#define HIDd 256
#define NEGf (-10000.0f)
#define PSTR 9            // partial-sum LDS stride (odd -> conflict-free)

// ---------------------------------------------------------------------------
// K0: Wt[k][n] (k<200, n<1024): n<512 -> W_ih_f[n][k], else W_ih_b[n-512][k]
// ---------------------------------------------------------------------------
__global__ __launch_bounds__(256) void k_wt(const float* __restrict__ Wf,
                                            const float* __restrict__ Wb,
                                            float* __restrict__ Wt) {
    int idx = blockIdx.x * 256 + threadIdx.x;
    if (idx >= Ee * 1024) return;
    int k = idx >> 10, n = idx & 1023;
    Wt[idx] = (n < G4) ? Wf[n * Ee + k] : Wb[(n - G4) * Ee + k];
}

// ---------------------------------------------------------------------------
// K1: fused gather+GEMM, BM=128 BN=256 BK=8 — double-buffered LDS, ONE
//   barrier per K-iter (was 2). Reuse of buf[k&1] at W_{k+2} is protected
//   by B_{k+1}: all threads passed W_{k+1}, which follows their C_k.
// ---------------------------------------------------------------------------
__global__ __launch_bounds__(256, 2) void k_gemm3(const int* __restrict__ sent,
                                                  const float* __restrict__ emb,
                                                  const float* __restrict__ Wt,
                                                  float* __restrict__ Uc,
                                                  int c0T, int CT, int unified) {
    __shared__ float As[2][8][128];
    __shared__ float Bs[2][8][256];
    __shared__ int   toks[128];

    int tid = threadIdx.x;
    int n0  = blockIdx.x * 256;
    int m0  = blockIdx.y * 128;
    int dz  = blockIdx.z;
    int ty  = tid >> 4, tx = tid & 15;

    if (tid < 128) {
        int m = m0 + tid;
        int it = m >> 6, b = m & 63;
        int t = unified ? it : (dz ? (Tt - 1 - (c0T + it)) : (c0T + it));
        toks[tid] = sent[b * Tt + t];
    }
    __syncthreads();

    int am = tid & 127, ak4 = tid >> 7;
    int brow = tid >> 5, bc4 = tid & 31;

    const float* aptr = emb + (size_t)toks[am] * Ee + ak4 * 4;
    int bcol0 = (unified ? 0 : dz * G4) + n0;
    const float* bptr = Wt + (size_t)brow * 1024 + bcol0 + bc4 * 4;

    float acc[8][16];
#pragma unroll
    for (int i = 0; i < 8; ++i)
#pragma unroll
        for (int j = 0; j < 16; ++j) acc[i][j] = 0.f;

    float4 av  = *(const float4*)(aptr);
    float4 bv0 = *(const float4*)(bptr);
    float4 bv1 = *(const float4*)(bptr + 128);

    const int NK = Ee / 8;                 // 25
    for (int k = 0; k < NK; ++k) {
        int cur = k & 1;
        As[cur][ak4 * 4 + 0][am] = av.x;   // W_k
        As[cur][ak4 * 4 + 1][am] = av.y;
        As[cur][ak4 * 4 + 2][am] = av.z;
        As[cur][ak4 * 4 + 3][am] = av.w;
        *(float4*)&Bs[cur][brow][bc4 * 4]       = bv0;
        *(float4*)&Bs[cur][brow][128 + bc4 * 4] = bv1;
        __syncthreads();                   // B_k (only barrier this iter)

        if (k + 1 < NK) {                  // G_{k+1}: latency hidden by C_k
            int kc = (k + 1) * 8;
            av  = *(const float4*)(aptr + kc);
            bv0 = *(const float4*)(bptr + (size_t)kc * 1024);
            bv1 = *(const float4*)(bptr + (size_t)kc * 1024 + 128);
        }

#pragma unroll
        for (int kk = 0; kk < 8; ++kk) {   // C_k
            float a_[8], b_[16];
            *(float4*)&a_[0] = *(const float4*)&As[cur][kk][ty * 8];
            *(float4*)&a_[4] = *(const float4*)&As[cur][kk][ty * 8 + 4];
#pragma unroll
            for (int q = 0; q < 4; ++q)
                *(float4*)&b_[4 * q] = *(const float4*)&Bs[cur][kk][tx * 4 + 64 * q];
#pragma unroll
            for (int i = 0; i < 8; ++i)
#pragma unroll
                for (int j = 0; j < 16; ++j)
                    acc[i][j] = fmaf(a_[i], b_[j], acc[i][j]);
        }
    }

    int dd   = unified ? (n0 >> 9) : dz;
    int ncol = unified ? (n0 & 511) : n0;
    float* base = Uc + (size_t)dd * ((size_t)CT * Bb * G4);
#pragma unroll
    for (int i = 0; i < 8; ++i) {
        float* dst = base + (size_t)(m0 + ty * 8 + i) * G4 + ncol + tx * 4;
#pragma unroll
        for (int q = 0; q < 4; ++q)
            *(float4*)(dst + 64 * q) = make_float4(acc[i][4 * q], acc[i][4 * q + 1],
                                                   acc[i][4 * q + 2], acc[i][4 * q + 3]);
    }
}

// ---------------------------------------------------------------------------
// K2: LSTM recurrence — EXACT round-3/11 k_lstm2 (proven 920us, conflicts=0).
// ---------------------------------------------------------------------------
__global__ __launch_bounds__(512, 2) void k_lstm2(const float* __restrict__ Uc,
                                                  const float* __restrict__ Whh_f,
                                                  const float* __restrict__ Whh_b,
                                                  const float* __restrict__ bih_f,
                                                  const float* __restrict__ bhh_f,
                                                  const float* __restrict__ bih_b,
                                                  const float* __restrict__ bhh_b,
                                                  const float* __restrict__ h0v,
                                                  const float* __restrict__ c0v,
                                                  const float* __restrict__ Wout,
                                                  float* __restrict__ hst,
                                                  float* __restrict__ cst,
                                                  float* __restrict__ pf,
                                                  int c0T, int CT, int first, int unified) {
    __shared__ float hsh[Hh];
    __shared__ float gsh[G4];
    __shared__ float ps[(G4 + Kk) * PSTR];

    int tid  = threadIdx.x;
    int lane = tid & 63, wv = tid >> 6;
    int b = blockIdx.x & 63, d = blockIdx.x >> 6;

    const float* Whh = d ? Whh_b : Whh_f;
    float bias = d ? (bih_b[tid] + bhh_b[tid]) : (bih_f[tid] + bhh_f[tid]);

    float w[8][16];
#pragma unroll
    for (int ri = 0; ri < 8; ++ri) {
        const float* wr = Whh + (size_t)(ri * 64 + lane) * Hh + wv * 16;
#pragma unroll
        for (int c4 = 0; c4 < 4; ++c4)
            *(float4*)&w[ri][c4 * 4] = *(const float4*)(wr + c4 * 4);
    }
    float wt[16];
    if (lane < Kk) {
        const float* wr = Wout + (size_t)lane * HIDd + d * Hh + wv * 16;
#pragma unroll
        for (int c4 = 0; c4 < 4; ++c4)
            *(float4*)&wt[c4 * 4] = *(const float4*)(wr + c4 * 4);
    }

    float cc = 0.f;
    if (tid < Hh) {
        int si = (d * Bb + b) * Hh + tid;
        hsh[tid] = first ? h0v[si] : hst[si];
        cc       = first ? c0v[si] : cst[si];
    }
    __syncthreads();

    const float* Ub = Uc + (size_t)d * ((size_t)CT * Bb * G4);
    int u0 = unified ? (d ? (Tt - 1) : 0) : 0;
    int us = unified ? (d ? -1 : 1) : 1;

    float ucur = Ub[(size_t)u0 * (Bb * G4) + b * G4 + tid];
    float unext = 0.f;

    for (int i = 0; i <= CT; ++i) {
        int last = (i == CT);
        // ---- P1: partial dots off current hsh = h(i-1) ----
        float hv[16];
        *(float4*)&hv[0]  = *(const float4*)&hsh[wv * 16];
        *(float4*)&hv[4]  = *(const float4*)&hsh[wv * 16 + 4];
        *(float4*)&hv[8]  = *(const float4*)&hsh[wv * 16 + 8];
        *(float4*)&hv[12] = *(const float4*)&hsh[wv * 16 + 12];

        if (lane < Kk) {
            float s = 0.f;
#pragma unroll
            for (int c = 0; c < 16; ++c) s = fmaf(wt[c], hv[c], s);
            ps[(G4 + lane) * PSTR + wv] = s;
        }
        if (!last) {
#pragma unroll
            for (int ri = 0; ri < 8; ++ri) {
                float s = 0.f;
#pragma unroll
                for (int c = 0; c < 16; ++c) s = fmaf(w[ri][c], hv[c], s);
                ps[(ri * 64 + lane) * PSTR + wv] = s;
            }
            if (i + 1 < CT)
                unext = Ub[(size_t)(u0 + (i + 1) * us) * (Bb * G4) + b * G4 + tid];
        }
        __syncthreads();

        // ---- P2: reduce + activate (thread tid owns gate tid) ----
        if (!last) {
            const float* pr = ps + (size_t)tid * PSTR;
            float s = ((pr[0] + pr[1]) + (pr[2] + pr[3])) +
                      ((pr[4] + pr[5]) + (pr[6] + pr[7]));
            s += ucur + bias;
            int gt = tid >> 7;                      // 0:i 1:f 2:g 3:o
            gsh[tid] = (gt == 2) ? tanhf(s) : 1.f / (1.f + expf(-s));
        }
        __syncthreads();

        // ---- P3: cell + tag emit of h(i-1) ----
        if (!last && tid < Hh) {
            float gi = gsh[tid], gf = gsh[Hh + tid];
            float gg = gsh[2 * Hh + tid], go = gsh[3 * Hh + tid];
            cc = gf * cc + gi * gg;
            hsh[tid] = go * tanhf(cc);
        }
        if (tid >= 128 && tid < 128 + Kk && i >= 1) {
            int k = tid - 128;
            const float* pr = ps + (size_t)(G4 + k) * PSTR;
            float s = ((pr[0] + pr[1]) + (pr[2] + pr[3])) +
                      ((pr[4] + pr[5]) + (pr[6] + pr[7]));
            int tp = c0T + i - 1;
            int tg = d ? (Tt - 1 - tp) : tp;
            pf[((size_t)(d * Bb + b) * Tt + tg) * Kk + k] = s;
        }
        __syncthreads();
        ucur = unext;
    }

    if (tid < Hh) {
        int si = (d * Bb + b) * Hh + tid;
        hst[si] = hsh[tid];
        cst[si] = cc;
    }
}

// ---------------------------------------------------------------------------
// K3: Viterbi, tree-argmax + 64-step LDS-staged feats (proven round 9/11)
// ---------------------------------------------------------------------------
#define CMB(av, ai, bv_, bi_, ov, oi)                         \
    { bool g = (bv_) > (av); ov = g ? (bv_) : (av); oi = g ? (bi_) : (ai); }

__global__ __launch_bounds__(64) void k_viterbi(const float* __restrict__ pf,
                                                const float* __restrict__ bout,
                                                const float* __restrict__ trans,
                                                float* __restrict__ out) {
    __shared__ unsigned char bptr[Tt * Kk];
    __shared__ float fsh[2][64][25];
    __shared__ float tsh[Kk];
    __shared__ unsigned char path[Tt];

    int lane = threadIdx.x;
    int b    = blockIdx.x;
    int half   = (lane >= Kk) ? 1 : 0;
    int n      = half ? (lane - Kk) : lane;
    int active = (lane < 2 * Kk);

    float tr[12];
    float bo = 0.f;
    if (active) {
#pragma unroll
        for (int j = 0; j < 12; ++j) tr[j] = trans[n * Kk + half * 12 + j];
        bo = bout[n];
    }
    float v = (lane == 0) ? 0.f : NEGf;   // START=0

    const float* p0 = pf + (size_t)b * Tt * Kk;
    const float* p1 = pf + (size_t)(Bb + b) * Tt * Kk;

    float4 r0[6], r1[6];
#pragma unroll
    for (int j = 0; j < 6; ++j) {
        int f = 4 * (lane + 64 * j);
        r0[j] = *(const float4*)(p0 + f);
        r1[j] = *(const float4*)(p1 + f);
    }
#pragma unroll
    for (int j = 0; j < 6; ++j) {
        int f = 4 * (lane + 64 * j);
        int s = f / 24, k = f - 24 * s;
        fsh[0][s][k + 0] = r0[j].x + r1[j].x;
        fsh[0][s][k + 1] = r0[j].y + r1[j].y;
        fsh[0][s][k + 2] = r0[j].z + r1[j].z;
        fsh[0][s][k + 3] = r0[j].w + r1[j].w;
    }

    for (int c = 0; c < 16; ++c) {
        int cur = c & 1;
        if (c + 1 < 16) {
            const float* q0 = p0 + (c + 1) * 1536;
            const float* q1 = p1 + (c + 1) * 1536;
#pragma unroll
            for (int j = 0; j < 6; ++j) {
                int f = 4 * (lane + 64 * j);
                r0[j] = *(const float4*)(q0 + f);
                r1[j] = *(const float4*)(q1 + f);
            }
        }

        for (int s = 0; s < 64; ++s) {
            int t = c * 64 + s;
            if (active) {
                int pb = half * 12;
                float sc[12];
#pragma unroll
                for (int j = 0; j < 12; ++j) sc[j] = __shfl(v, pb + j) + tr[j];

                float l1v[6]; int l1i[6];
#pragma unroll
                for (int j = 0; j < 6; ++j)
                    CMB(sc[2 * j], 2 * j, sc[2 * j + 1], 2 * j + 1, l1v[j], l1i[j]);
                float l2v[3]; int l2i[3];
#pragma unroll
                for (int j = 0; j < 3; ++j)
                    CMB(l1v[2 * j], l1i[2 * j], l1v[2 * j + 1], l1i[2 * j + 1],
                        l2v[j], l2i[j]);
                float dv; int di;
                CMB(l2v[0], l2i[0], l2v[1], l2i[1], dv, di);
                float best; int bp;
                CMB(dv, di, l2v[2], l2i[2], best, bp);
                bp += pb;

                float ob  = __shfl(best, n + Kk);
                int   obp = __shfl(bp,   n + Kk);
                if (half == 0) {
                    if (ob > best) { best = ob; bp = obp; }
                    v = best + fsh[cur][s][n] + bo;
                    bptr[t * Kk + n] = (unsigned char)bp;
                }
            }
        }

        if (c + 1 < 16) {
#pragma unroll
            for (int j = 0; j < 6; ++j) {
                int f = 4 * (lane + 64 * j);
                int s = f / 24, k = f - 24 * s;
                fsh[cur ^ 1][s][k + 0] = r0[j].x + r1[j].x;
                fsh[cur ^ 1][s][k + 1] = r0[j].y + r1[j].y;
                fsh[cur ^ 1][s][k + 2] = r0[j].z + r1[j].z;
                fsh[cur ^ 1][s][k + 3] = r0[j].w + r1[j].w;
            }
        }
    }

    if (half == 0 && lane < Kk) tsh[n] = v + trans[1 * Kk + n];   // STOP=1
    __syncthreads();

    if (lane == 0) {
        float bestv = tsh[0];
        int tag = 0;
        for (int q = 1; q < Kk; ++q)
            if (tsh[q] > bestv) { bestv = tsh[q]; tag = q; }
        out[b] = bestv;
        for (int t = Tt - 1; t >= 1; --t) {
            path[t] = (unsigned char)tag;
            tag = bptr[t * Kk + tag];
        }
        path[0] = (unsigned char)tag;
    }
    __syncthreads();

    float* otag = out + Bb + (size_t)b * Tt;
    for (int t = lane; t < Tt; t += 64) otag[t] = (float)path[t];
}

// ---------------------------------------------------------------------------
// host launcher
// ---------------------------------------------------------------------------
extern "C" void kernel_launch(void* const* d_in, const int* in_sizes, int n_in,
                              void* d_out, int out_size, void* d_ws, size_t ws_size,
                              hipStream_t stream) {
    const int*   sent  = (const int*)d_in[0];
    const float* emb   = (const float*)d_in[2];
    const float* Wih_f = (const float*)d_in[3];
    const float* Whh_f = (const float*)d_in[4];
    const float* bih_f = (const float*)d_in[5];
    const float* bhh_f = (const float*)d_in[6];
    const float* Wih_b = (const float*)d_in[7];
    const float* Whh_b = (const float*)d_in[8];
    const float* bih_b = (const float*)d_in[9];
    const float* bhh_b = (const float*)d_in[10];
    const float* h0    = (const float*)d_in[11];
    const float* c0    = (const float*)d_in[12];
    const float* Wout  = (const float*)d_in[13];
    const float* bout  = (const float*)d_in[14];
    const float* trans = (const float*)d_in[15];

    float* ws  = (float*)d_ws;
    float* Wt  = ws;                       //   204,800 f
    float* pf  = Wt + 204800;              // 3,145,728 f
    float* hst = pf + 3145728;             //    16,384 f
    float* cst = hst + 16384;              //    16,384 f
    float* Uc  = cst + 16384;

    const size_t fixedf = 204800 + 3145728 + 16384 + 16384;
    size_t needU = (size_t)2 * Tt * Bb * G4;
    int unified = ((fixedf + needU) * 4 <= ws_size);

    k_wt<<<(Ee * 1024 + 255) / 256, 256, 0, stream>>>(Wih_f, Wih_b, Wt);

    if (unified) {
        k_gemm3<<<dim3(4, 512, 1), 256, 0, stream>>>(sent, emb, Wt, Uc, 0, Tt, 1);
        k_lstm2<<<128, 512, 0, stream>>>(Uc, Whh_f, Whh_b, bih_f, bhh_f,
                                         bih_b, bhh_b, h0, c0, Wout,
                                         hst, cst, pf, 0, Tt, 1, 1);
    } else {
        int CT = 64;
        const int cands[3] = {512, 256, 128};
        for (int ci = 0; ci < 3; ++ci)
            if ((fixedf + (size_t)2 * cands[ci] * Bb * G4) * 4 <= ws_size) {
                CT = cands[ci]; break;
            }
        int NC = Tt / CT;
        for (int cix = 0; cix < NC; ++cix) {
            k_gemm3<<<dim3(2, CT * 64 / 128, 2), 256, 0, stream>>>(
                sent, emb, Wt, Uc, cix * CT, CT, 0);
            k_lstm2<<<128, 512, 0, stream>>>(Uc, Whh_f, Whh_b, bih_f, bhh_f,
                                             bih_b, bhh_b, h0, c0, Wout,
                                             hst, cst, pf, cix * CT, CT,
                                             cix == 0, 0);
        }
    }

    k_viterbi<<<Bb, 64, 0, stream>>>(pf, bout, trans, (float*)d_out);
}